// Round 26
// baseline (58.828 us; speedup 1.0000x reference)
//
#include <hip/hip_runtime.h>
#include <math.h>

typedef __attribute__((ext_vector_type(4))) float f32x4;
typedef __attribute__((ext_vector_type(8))) int int8v;

#define NP 14400     // real patches per video
#define NPK 14592    // padded rows/cols (912 groups of 16; 152 groups of 96)
#define NSEG 16      // column segments (912 col-groups = 57 per segment)
#define NIT 57       // 16-col groups per segment
#define GRPB 1536    // bytes per 16-col group (16 cols * 96 k * 1B)

// ---- manual OCP e4m3fn encode/decode (RNE, saturating; prep-only cost) ----
__device__ __forceinline__ unsigned char f2fp8(float x) {
  unsigned u = __float_as_uint(x);
  unsigned sign = (u >> 31) << 7;
  int exp = (int)((u >> 23) & 0xFF) - 127;
  unsigned man = u & 0x7FFFFF;
  if (exp >= -6) {
    unsigned keep = man >> 20;
    unsigned rest = man & 0xFFFFF;
    keep += (rest > 0x80000u) || (rest == 0x80000u && (keep & 1));
    int e8 = exp + 7;
    if (keep == 8) { keep = 0; e8 += 1; }
    if (e8 > 15 || (e8 == 15 && keep == 7)) return sign | 0x7E;  // sat 448
    return sign | ((unsigned)e8 << 3) | keep;
  } else {
    float a = fabsf(x);
    int q = (int)(a * 512.f + 0.5f);       // subnormal step 2^-9
    if (q >= 8) return sign | 0x08;        // rounds up to 2^-6
    return sign | (unsigned)q;
  }
}
__device__ __forceinline__ float fp82f(unsigned char b) {
  unsigned e = (b >> 3) & 15, m = b & 7;
  float v = (e == 0) ? ldexpf((float)m, -9) : ldexpf((float)(8 + m), (int)e - 10);
  return (b & 0x80) ? -v : v;
}

// MX fragment layout, 96 real k bytes per column: group g = p>>4 is 1536 B;
// element (p,d) d<96 at g*1536 + ((p&15) + 16*(d>>5))*32 + (d&31).
// MFMA lane l holds idx=l&15, k-group=l>>4 (32 k bytes). Lanes 0..47 load
// their own bytes; lanes 48..63 (k-group 3) RE-READ k-group 2's bytes and
// the A operand for those lanes is zeroed -> group-3 products are exactly 0.
__device__ __forceinline__ size_t f8idx(int p, int d) {
  return (size_t)(p >> 4) * GRPB
       + (size_t)((((p & 15) + 16 * (d >> 5)) * 32) + (d & 31));
}

// ---------------- prep: patches -> fp8 in MX fragment order ---------------
// Q: k 0..74 = fp8(-2*q), 75..95 = 0; qn = fp32 exact norm.
// K: k 0..74 = fp8(k), 75..95 = 0;   kn = fp32 norm of fp8-decoded k.
// Pad rows/cols (p >= NP): zero data; kn = 3.39e38 (never wins); qn = 0.
__global__ __launch_bounds__(256) void prep_kernel(
    const float* __restrict__ resv, const float* __restrict__ valv,
    unsigned char* __restrict__ Qb, unsigned char* __restrict__ Kb,
    float* __restrict__ qn, float* __restrict__ kn,
    unsigned* __restrict__ rminb) {
  int w = threadIdx.x >> 6;
  int lane = threadIdx.x & 63;
  int pg = blockIdx.x * 4 + w;          // 0..29183
  int isK = pg >= NPK;
  int p = isK ? pg - NPK : pg;          // 0..14591

  float v0 = 0.f, v1 = 0.f;
  if (p < NP) {
    const float* src = isK ? valv : resv;
    int t = p / 3600; int rem = p - t * 3600;
    int y = rem / 60;  int x = rem - y * 60;
    {
      int d = lane;  // < 75 always
      int c = d / 25; int r = d - c * 25; int dy = r / 5; int dx = r - dy * 5;
      v0 = src[((c * 4 + t) * 64 + (y + dy)) * 64 + (x + dx)];
    }
    if (lane < 11) {
      int d = lane + 64;
      int c = d / 25; int r = d - c * 25; int dy = r / 5; int dx = r - dy * 5;
      v1 = src[((c * 4 + t) * 64 + (y + dy)) * 64 + (x + dx)];
    }
  }

  unsigned char b0, b1;
  if (isK) { b0 = f2fp8(v0); b1 = f2fp8(v1); }
  else     { b0 = f2fp8(-2.f * v0); b1 = f2fp8(-2.f * v1); }

  float sq;
  if (isK) {
    float d0 = fp82f(b0), d1 = fp82f(b1);   // norm of quantized keys
    sq = d0 * d0 + d1 * d1;
  } else {
    sq = v0 * v0 + v1 * v1;                 // exact query norm
  }
  #pragma unroll
  for (int off = 1; off < 64; off <<= 1) sq += __shfl_xor(sq, off, 64);

  unsigned char* dst = isK ? Kb : Qb;
  dst[f8idx(p, lane)] = b0;                     // k-groups 0,1 (d 0..63)
  if (lane < 32) dst[f8idx(p, lane + 64)] = b1; // k-group 2 (d 64..95)
  if (lane == 0) {
    if (isK) kn[p] = (p < NP) ? sq : 3.39e38f;
    else { qn[p] = sq; rminb[p] = 0xFFFFFFFFu; }
  }
}

// ------- main: ONE-WAVE blocks, 96x16 tiles, MX-scaled fp8 K=128 ----------
// 2432 blocks = 8 x 304 (bijective). 6 MFMAs per 1536-B B-tile (1.5x fewer
// bytes per MFMA than 64-row tiles), kn via C operand, depth-2 B regs.
__global__ __launch_bounds__(64, 4) void knn_kernel(
    const unsigned char* __restrict__ Qb, const unsigned char* __restrict__ Kb,
    const float* __restrict__ kn, unsigned* __restrict__ rminb) {
  int b = blockIdx.x;
  int lin = (b & 7) * 304 + (b >> 3);   // bijective: 2432 = 8*304
  int ns = lin / 152, rowblk = lin - ns * 152;
  int brow = rowblk * 96;
  int lane = threadIdx.x;               // 0..63
  int l15 = lane & 15, l4 = lane >> 4;
  int bl = (lane < 48 ? lane : lane - 16) * 32;   // lane byte base, <=1504

  const char* gW = (const char*)Kb + (size_t)(ns * NIT) * GRPB + bl;
  const char* Aw = (const char*)Qb + (size_t)(rowblk * 6) * GRPB + bl;
  int colbase = ns * 912 + l15;

  // A fragments: 96 rows x 96 k = 6 row-tiles x 8 VGPR; lanes>=48 zeroed
  int8v af[6];
  #pragma unroll
  for (int rt = 0; rt < 6; ++rt) {
    int8v t = *(const int8v*)(Aw + rt * GRPB);
    if (lane >= 48) {
      #pragma unroll
      for (int i = 0; i < 8; ++i) t[i] = 0;
    }
    af[rt] = t;
  }

  float rmin[6][4];
  #pragma unroll
  for (int rt = 0; rt < 6; ++rt)
    #pragma unroll
    for (int j = 0; j < 4; ++j) rmin[rt][j] = INFINITY;

  int8v bbuf[2]; float kvb[2];          // depth-2, literal indices only

  auto loadB = [&](int bi, int it) {
    bbuf[bi] = *(const int8v*)(gW + (size_t)it * GRPB);
    kvb[bi] = kn[colbase + it * 16];
  };

  auto compute = [&](int bi) {
    float kv = kvb[bi];
    f32x4 ci = {kv, kv, kv, kv};
    f32x4 acc[6];
    #pragma unroll
    for (int rt = 0; rt < 6; ++rt)
      acc[rt] = __builtin_amdgcn_mfma_scale_f32_16x16x128_f8f6f4(
          af[rt], bbuf[bi], ci, 0, 0,               // cbsz=0 blgp=0: e4m3
          0, 0x7F7F7F7F, 0, 0x7F7F7F7F);            // scales = 1.0 (e8m0 127)
    #pragma unroll
    for (int rt = 0; rt < 6; ++rt)
      #pragma unroll
      for (int j = 0; j < 4; ++j)
        rmin[rt][j] = fminf(rmin[rt][j], acc[rt][j]);
  };

  loadB(0, 0);
  loadB(1, 1);

  // 57 iters: 27 doubles (0..53) + 3-iter tail; loads 2 iters ahead
  int k = 0;
  #pragma unroll 1
  for (int tri = 0; tri < 27; ++tri, k += 2) {
    compute(0); loadB(0, k + 2);
    compute(1); loadB(1, k + 3);
  }
  // k == 54; in flight: (0,54),(1,55)
  compute(0); loadB(0, 56);   // iter 54
  compute(1);                  // iter 55
  compute(0);                  // iter 56

  // min over the 16 key-cols (l15 lanes), then device atomicMin per row
  #pragma unroll
  for (int rt = 0; rt < 6; ++rt)
    #pragma unroll
    for (int j = 0; j < 4; ++j) {
      float m = rmin[rt][j];
      m = fminf(m, __shfl_xor(m, 1, 64));
      m = fminf(m, __shfl_xor(m, 2, 64));
      m = fminf(m, __shfl_xor(m, 4, 64));
      m = fminf(m, __shfl_xor(m, 8, 64));
      if (l15 == 0) {
        unsigned bu = __float_as_uint(m);
        unsigned tu = bu ^ (unsigned)(((int)bu >> 31) | (int)0x80000000);
        atomicMin(&rminb[brow + rt * 16 + l4 * 4 + j], tu);
      }
    }
}

// ------ final: decode + add qn + deterministic sum (one block) ------------
__global__ __launch_bounds__(1024) void final_kernel(
    const unsigned* __restrict__ rminb, const float* __restrict__ qn,
    float* __restrict__ out) {
  int t = threadIdx.x;
  float s = 0.f;
  for (int i = t; i < NP; i += 1024) {
    unsigned u = rminb[i];
    unsigned bu = (u & 0x80000000u) ? (u ^ 0x80000000u) : ~u;
    s += __uint_as_float(bu) + qn[i];
  }
  #pragma unroll
  for (int off = 32; off; off >>= 1) s += __shfl_down(s, off, 64);
  __shared__ float red[16];
  if ((t & 63) == 0) red[t >> 6] = s;
  __syncthreads();
  if (t == 0) {
    float tot = 0.f;
    #pragma unroll
    for (int i2 = 0; i2 < 16; ++i2) tot += red[i2];
    out[0] = tot;
  }
}

extern "C" void kernel_launch(void* const* d_in, const int* in_sizes, int n_in,
                              void* d_out, int out_size, void* d_ws, size_t ws_size,
                              hipStream_t stream) {
  const float* resv = (const float*)d_in[0];
  const float* valv = (const float*)d_in[1];
  char* ws = (char*)d_ws;
  unsigned char* Qb = (unsigned char*)ws;            // 1,400,832 B
  unsigned char* Kb = (unsigned char*)(ws + 1400832);// 1,400,832 B
  float* qn         = (float*)(ws + 2801664);        //    58,368 B
  float* kn         = (float*)(ws + 2860032);        //    58,368 B
  unsigned* rminb   = (unsigned*)(ws + 2918400);     //    58,368 B
  float* out = (float*)d_out;

  prep_kernel<<<7296, 256, 0, stream>>>(resv, valv, Qb, Kb, qn, kn, rminb);
  knn_kernel<<<2432, 64, 0, stream>>>(Qb, Kb, kn, rminb);
  final_kernel<<<1, 1024, 0, stream>>>(rminb, qn, out);
}

// Round 27
// 44.598 us; speedup vs baseline: 1.3191x; 1.3191x over previous
//
#include <hip/hip_runtime.h>
#include <math.h>

typedef __attribute__((ext_vector_type(4))) float f32x4;
typedef __attribute__((ext_vector_type(8))) int int8v;

#define NP 14400     // real patches per video
#define NPK 14592    // padded rows/cols (912 groups of 16)
#define NSEG 16      // column segments (912 col-groups = 57 per segment)
#define NIT 57       // 16-col groups per segment
#define GRPB 1536    // bytes per 16-col group (16 cols * 96 k * 1B)

// ---- manual OCP e4m3fn encode/decode (RNE, saturating; prep-only cost) ----
__device__ __forceinline__ unsigned char f2fp8(float x) {
  unsigned u = __float_as_uint(x);
  unsigned sign = (u >> 31) << 7;
  int exp = (int)((u >> 23) & 0xFF) - 127;
  unsigned man = u & 0x7FFFFF;
  if (exp >= -6) {
    unsigned keep = man >> 20;
    unsigned rest = man & 0xFFFFF;
    keep += (rest > 0x80000u) || (rest == 0x80000u && (keep & 1));
    int e8 = exp + 7;
    if (keep == 8) { keep = 0; e8 += 1; }
    if (e8 > 15 || (e8 == 15 && keep == 7)) return sign | 0x7E;  // sat 448
    return sign | ((unsigned)e8 << 3) | keep;
  } else {
    float a = fabsf(x);
    int q = (int)(a * 512.f + 0.5f);       // subnormal step 2^-9
    if (q >= 8) return sign | 0x08;        // rounds up to 2^-6
    return sign | (unsigned)q;
  }
}
__device__ __forceinline__ float fp82f(unsigned char b) {
  unsigned e = (b >> 3) & 15, m = b & 7;
  float v = (e == 0) ? ldexpf((float)m, -9) : ldexpf((float)(8 + m), (int)e - 10);
  return (b & 0x80) ? -v : v;
}

// MX fragment layout, 96 real k bytes per column: group g = p>>4 is 1536 B;
// element (p,d) d<96 at g*1536 + ((p&15) + 16*(d>>5))*32 + (d&31).
// MFMA lane l holds idx=l&15, k-group=l>>4 (32 k bytes). Lanes 0..47 load
// their own bytes; lanes 48..63 (k-group 3) RE-READ k-group 2's bytes and
// the A operand for those lanes is zeroed -> group-3 products are exactly 0.
__device__ __forceinline__ size_t f8idx(int p, int d) {
  return (size_t)(p >> 4) * GRPB
       + (size_t)((((p & 15) + 16 * (d >> 5)) * 32) + (d & 31));
}

// ---------------- prep: patches -> fp8 in MX fragment order ---------------
// Q: k 0..74 = fp8(-2*q), 75..95 = 0; qn = fp32 exact norm.
// K: k 0..74 = fp8(k), 75..95 = 0;   kn = fp32 norm of fp8-decoded k.
// Pad rows/cols (p >= NP): zero data; kn = 3.39e38 (never wins); qn = 0.
__global__ __launch_bounds__(256) void prep_kernel(
    const float* __restrict__ resv, const float* __restrict__ valv,
    unsigned char* __restrict__ Qb, unsigned char* __restrict__ Kb,
    float* __restrict__ qn, float* __restrict__ kn,
    unsigned* __restrict__ rminb) {
  int w = threadIdx.x >> 6;
  int lane = threadIdx.x & 63;
  int pg = blockIdx.x * 4 + w;          // 0..29183
  int isK = pg >= NPK;
  int p = isK ? pg - NPK : pg;          // 0..14591

  float v0 = 0.f, v1 = 0.f;
  if (p < NP) {
    const float* src = isK ? valv : resv;
    int t = p / 3600; int rem = p - t * 3600;
    int y = rem / 60;  int x = rem - y * 60;
    {
      int d = lane;  // < 75 always
      int c = d / 25; int r = d - c * 25; int dy = r / 5; int dx = r - dy * 5;
      v0 = src[((c * 4 + t) * 64 + (y + dy)) * 64 + (x + dx)];
    }
    if (lane < 11) {
      int d = lane + 64;
      int c = d / 25; int r = d - c * 25; int dy = r / 5; int dx = r - dy * 5;
      v1 = src[((c * 4 + t) * 64 + (y + dy)) * 64 + (x + dx)];
    }
  }

  unsigned char b0, b1;
  if (isK) { b0 = f2fp8(v0); b1 = f2fp8(v1); }
  else     { b0 = f2fp8(-2.f * v0); b1 = f2fp8(-2.f * v1); }

  float sq;
  if (isK) {
    float d0 = fp82f(b0), d1 = fp82f(b1);   // norm of quantized keys
    sq = d0 * d0 + d1 * d1;
  } else {
    sq = v0 * v0 + v1 * v1;                 // exact query norm
  }
  #pragma unroll
  for (int off = 1; off < 64; off <<= 1) sq += __shfl_xor(sq, off, 64);

  unsigned char* dst = isK ? Kb : Qb;
  dst[f8idx(p, lane)] = b0;                     // k-groups 0,1 (d 0..63)
  if (lane < 32) dst[f8idx(p, lane + 64)] = b1; // k-group 2 (d 64..95)
  if (lane == 0) {
    if (isK) kn[p] = (p < NP) ? sq : 3.39e38f;
    else { qn[p] = sq; rminb[p] = 0xFFFFFFFFu; }
  }
}

// ------- main: ONE-WAVE blocks, 64x16 tiles, MX-scaled fp8 K=128 ----------
// 3648 blocks = 8 x 456 (bijective). 4 MFMAs/iter (one 16x16x128 per
// row-tile, scales = 1.0), kn folded via the C operand. Depth-2 B regs.
// Only 1536 unique B bytes/iter: lanes 48..63 re-read k-group 2 (their A
// operand is zero, so the duplicated products vanish).
__global__ __launch_bounds__(64, 4) void knn_kernel(
    const unsigned char* __restrict__ Qb, const unsigned char* __restrict__ Kb,
    const float* __restrict__ kn, unsigned* __restrict__ rminb) {
  int b = blockIdx.x;
  int lin = (b & 7) * 456 + (b >> 3);   // bijective: 3648 = 8*456
  int ns = lin / 228, rowblk = lin - ns * 228;
  int brow = rowblk * 64;
  int lane = threadIdx.x;               // 0..63
  int l15 = lane & 15, l4 = lane >> 4;
  int bl = (lane < 48 ? lane : lane - 16) * 32;   // lane byte base, <=1504

  const char* gW = (const char*)Kb + (size_t)(ns * NIT) * GRPB + bl;
  const char* Aw = (const char*)Qb + (size_t)(rowblk * 4) * GRPB + bl;
  int colbase = ns * 912 + l15;

  // A fragments: 64 rows x 96 k = 4 row-tiles x 8 VGPR; lanes>=48 zeroed
  int8v af[4];
  #pragma unroll
  for (int rt = 0; rt < 4; ++rt) {
    int8v t = *(const int8v*)(Aw + rt * GRPB);
    if (lane >= 48) {
      #pragma unroll
      for (int i = 0; i < 8; ++i) t[i] = 0;
    }
    af[rt] = t;
  }

  float rmin[4][4];
  #pragma unroll
  for (int rt = 0; rt < 4; ++rt)
    #pragma unroll
    for (int j = 0; j < 4; ++j) rmin[rt][j] = INFINITY;

  int8v bbuf[2]; float kvb[2];          // depth-2, literal indices only

  auto loadB = [&](int bi, int it) {
    bbuf[bi] = *(const int8v*)(gW + (size_t)it * GRPB);
    kvb[bi] = kn[colbase + it * 16];
  };

  auto compute = [&](int bi) {
    float kv = kvb[bi];
    f32x4 ci = {kv, kv, kv, kv};
    f32x4 acc[4];
    #pragma unroll
    for (int rt = 0; rt < 4; ++rt)
      acc[rt] = __builtin_amdgcn_mfma_scale_f32_16x16x128_f8f6f4(
          af[rt], bbuf[bi], ci, 0, 0,               // cbsz=0 blgp=0: e4m3
          0, 0x7F7F7F7F, 0, 0x7F7F7F7F);            // scales = 1.0 (e8m0 127)
    #pragma unroll
    for (int rt = 0; rt < 4; ++rt)
      #pragma unroll
      for (int j = 0; j < 4; ++j)
        rmin[rt][j] = fminf(rmin[rt][j], acc[rt][j]);
  };

  loadB(0, 0);
  loadB(1, 1);

  // 57 iters: 27 doubles (0..53) + 3-iter tail; loads 2 iters ahead
  int k = 0;
  #pragma unroll 1
  for (int tri = 0; tri < 27; ++tri, k += 2) {
    compute(0); loadB(0, k + 2);
    compute(1); loadB(1, k + 3);
  }
  // k == 54; in flight: (0,54),(1,55)
  compute(0); loadB(0, 56);   // iter 54
  compute(1);                  // iter 55
  compute(0);                  // iter 56

  // min over the 16 key-cols (l15 lanes), then device atomicMin per row
  #pragma unroll
  for (int rt = 0; rt < 4; ++rt)
    #pragma unroll
    for (int j = 0; j < 4; ++j) {
      float m = rmin[rt][j];
      m = fminf(m, __shfl_xor(m, 1, 64));
      m = fminf(m, __shfl_xor(m, 2, 64));
      m = fminf(m, __shfl_xor(m, 4, 64));
      m = fminf(m, __shfl_xor(m, 8, 64));
      if (l15 == 0) {
        unsigned bu = __float_as_uint(m);
        unsigned tu = bu ^ (unsigned)(((int)bu >> 31) | (int)0x80000000);
        atomicMin(&rminb[brow + rt * 16 + l4 * 4 + j], tu);
      }
    }
}

// ------ final: decode + add qn + deterministic sum (one block) ------------
__global__ __launch_bounds__(1024) void final_kernel(
    const unsigned* __restrict__ rminb, const float* __restrict__ qn,
    float* __restrict__ out) {
  int t = threadIdx.x;
  float s = 0.f;
  for (int i = t; i < NP; i += 1024) {
    unsigned u = rminb[i];
    unsigned bu = (u & 0x80000000u) ? (u ^ 0x80000000u) : ~u;
    s += __uint_as_float(bu) + qn[i];
  }
  #pragma unroll
  for (int off = 32; off; off >>= 1) s += __shfl_down(s, off, 64);
  __shared__ float red[16];
  if ((t & 63) == 0) red[t >> 6] = s;
  __syncthreads();
  if (t == 0) {
    float tot = 0.f;
    #pragma unroll
    for (int i2 = 0; i2 < 16; ++i2) tot += red[i2];
    out[0] = tot;
  }
}

extern "C" void kernel_launch(void* const* d_in, const int* in_sizes, int n_in,
                              void* d_out, int out_size, void* d_ws, size_t ws_size,
                              hipStream_t stream) {
  const float* resv = (const float*)d_in[0];
  const float* valv = (const float*)d_in[1];
  char* ws = (char*)d_ws;
  unsigned char* Qb = (unsigned char*)ws;            // 1,400,832 B
  unsigned char* Kb = (unsigned char*)(ws + 1400832);// 1,400,832 B
  float* qn         = (float*)(ws + 2801664);        //    58,368 B
  float* kn         = (float*)(ws + 2860032);        //    58,368 B
  unsigned* rminb   = (unsigned*)(ws + 2918400);     //    58,368 B
  float* out = (float*)d_out;

  prep_kernel<<<7296, 256, 0, stream>>>(resv, valv, Qb, Kb, qn, kn, rminb);
  knn_kernel<<<3648, 64, 0, stream>>>(Qb, Kb, kn, rminb);
  final_kernel<<<1, 1024, 0, stream>>>(rminb, qn, out);
}